// Round 1
// baseline (547.945 us; speedup 1.0000x reference)
//
#include <hip/hip_runtime.h>
#include <stdint.h>

#define NN 100000
#define NE 1600000
#define NR 4
#define FD 128
#define KT 640     // 512 (rel) + 128 (root)
#define NQ 1024
#define HIDN 256

using u16 = unsigned short;
using u32 = unsigned int;
typedef __attribute__((ext_vector_type(8))) __bf16 bf16x8;
typedef __attribute__((ext_vector_type(4))) float f32x4;

__device__ __forceinline__ u16 f2b(float f) {
    u32 u = __builtin_bit_cast(u32, f);
    u32 r = u + 0x7FFFu + ((u >> 16) & 1u);   // round-to-nearest-even
    return (u16)(r >> 16);
}
__device__ __forceinline__ float b2f(u16 h) {
    u32 u = ((u32)h) << 16;
    return __builtin_bit_cast(float, u);
}
__device__ __forceinline__ u32 pack2(float a, float b) {
    return (u32)f2b(a) | ((u32)f2b(b) << 16);
}

// ---------- CSR build ----------
__global__ __launch_bounds__(256) void count_kernel(const int* __restrict__ ei,
                                                    const int* __restrict__ et,
                                                    int* __restrict__ deg_key) {
    int e = blockIdx.x * 256 + threadIdx.x;
    if (e >= NE) return;
    int dst = ei[NE + e];
    int r = et[e];
    atomicAdd(&deg_key[dst * NR + r], 1);
}

__global__ __launch_bounds__(256) void chunk_sum(const int* __restrict__ deg_key,
                                                 int* __restrict__ chunkTot) {
    __shared__ int sm[256];
    int b = blockIdx.x, t = threadIdx.x;
    int base = b * 1024 + t * 4;
    int s = 0;
    for (int j = 0; j < 4; ++j) {
        int d = base + j;
        if (d < NN)
            s += deg_key[4 * d] + deg_key[4 * d + 1] + deg_key[4 * d + 2] + deg_key[4 * d + 3];
    }
    sm[t] = s;
    __syncthreads();
    for (int o2 = 128; o2 > 0; o2 >>= 1) {
        if (t < o2) sm[t] += sm[t + o2];
        __syncthreads();
    }
    if (t == 0) chunkTot[b] = sm[0];
}

#define NCH ((NN + 1023) / 1024)   // 98

__global__ void scan_chunks(const int* __restrict__ chunkTot,
                            int* __restrict__ chunkOff,
                            int* __restrict__ offs) {
    int l = threadIdx.x;  // 64 threads, one wave
    int v0 = (l < NCH) ? chunkTot[l] : 0;
    int v1 = (l + 64 < NCH) ? chunkTot[l + 64] : 0;
    int i0 = v0;
    for (int o2 = 1; o2 < 64; o2 <<= 1) {
        int n = __shfl_up(i0, o2);
        if (l >= o2) i0 += n;
    }
    int T0 = __shfl(i0, 63);
    int i1 = v1;
    for (int o2 = 1; o2 < 64; o2 <<= 1) {
        int n = __shfl_up(i1, o2);
        if (l >= o2) i1 += n;
    }
    if (l < NCH) chunkOff[l] = i0 - v0;
    if (l + 64 < NCH) chunkOff[l + 64] = T0 + i1 - v1;
    if (l == 0) offs[NN] = NE;
}

__global__ __launch_bounds__(256) void write_offsets(const int* __restrict__ deg_key,
                                                     const int* __restrict__ chunkOff,
                                                     int* __restrict__ offs,
                                                     int* __restrict__ cursor) {
    __shared__ int sm[256];
    int b = blockIdx.x, t = threadIdx.x;
    int base = b * 1024 + t * 4;
    int g[4];
    int s = 0;
    for (int j = 0; j < 4; ++j) {
        int d = base + j;
        g[j] = (d < NN) ? (deg_key[4 * d] + deg_key[4 * d + 1] + deg_key[4 * d + 2] + deg_key[4 * d + 3]) : 0;
        s += g[j];
    }
    sm[t] = s;
    __syncthreads();
    for (int o2 = 1; o2 < 256; o2 <<= 1) {
        int v = (t >= o2) ? sm[t - o2] : 0;
        __syncthreads();
        sm[t] += v;
        __syncthreads();
    }
    int excl = sm[t] - s + chunkOff[b];
    for (int j = 0; j < 4; ++j) {
        int d = base + j;
        if (d < NN) {
            offs[d] = excl;
            cursor[d] = excl;
            excl += g[j];
        }
    }
}

__global__ __launch_bounds__(256) void scatter_kernel(const int* __restrict__ ei,
                                                      const int* __restrict__ et,
                                                      int* __restrict__ cursor,
                                                      int* __restrict__ spack) {
    int e = blockIdx.x * 256 + threadIdx.x;
    if (e >= NE) return;
    int src = ei[e];
    int dst = ei[NE + e];
    int r = et[e];
    int pos = atomicAdd(&cursor[dst], 1);
    spack[pos] = src | (r << 17);   // src < 2^17, r < 4
}

// ---------- conversions / weight prep ----------
__global__ __launch_bounds__(256) void cvt_bf16(const float* __restrict__ in,
                                                u16* __restrict__ outp, int n) {
    int i = blockIdx.x * 256 + threadIdx.x;
    int idx = i * 4;
    if (idx + 3 >= n) {
        for (int j = idx; j < n; ++j) outp[j] = f2b(in[j]);
        return;
    }
    float4 v = *(const float4*)(in + idx);
    u32 lo = (u32)f2b(v.x) | ((u32)f2b(v.y) << 16);
    u32 hi = (u32)f2b(v.z) | ((u32)f2b(v.w) << 16);
    *(uint2*)(outp + idx) = make_uint2(lo, hi);
}

// Bt[o][k]: k<512 -> W_rel[(k/128)][k%128][o] == Wrel[k*128+o]; k>=512 -> Wroot[(k-512)*128+o]
__global__ __launch_bounds__(256) void prep_B(const float* __restrict__ Wrel,
                                              const float* __restrict__ Wroot,
                                              u16* __restrict__ Bt) {
    int i = blockIdx.x * 256 + threadIdx.x;
    if (i >= FD * KT) return;
    int k = i % KT;
    int o = i / KT;
    float v = (k < 512) ? Wrel[(size_t)k * FD + o] : Wroot[(size_t)(k - 512) * FD + o];
    Bt[i] = f2b(v);
}

// ---------- aggregation: one wave per output row ----------
__global__ __launch_bounds__(256) void agg_kernel(const int* __restrict__ offs,
                                                  const int* __restrict__ deg_key,
                                                  const int* __restrict__ spack,
                                                  const u16* __restrict__ feat,
                                                  u16* __restrict__ Aout,
                                                  int rows, int node_base,
                                                  const int* __restrict__ nest,
                                                  const int* __restrict__ food,
                                                  int qmode) {
    int wid = threadIdx.x >> 6, lane = threadIdx.x & 63;
    int row = blockIdx.x * 4 + wid;
    if (row >= rows) return;
    int node;
    if (qmode) node = (row < NQ) ? nest[row] : food[row - NQ];
    else node = node_base + row;
    int c = lane * 2;
    float a00 = 0, a01 = 0, a10 = 0, a11 = 0, a20 = 0, a21 = 0, a30 = 0, a31 = 0;
    int s = offs[node], e = offs[node + 1];
    for (int i = s; i < e; ++i) {
        int pk = __builtin_amdgcn_readfirstlane(spack[i]);  // wave-uniform edge
        int src = pk & 0x1FFFF;
        int r = pk >> 17;
        u32 v = *(const u32*)(feat + (size_t)src * FD + c);
        float f0 = b2f((u16)(v & 0xFFFFu));
        float f1 = b2f((u16)(v >> 16));
        if (r == 0)      { a00 += f0; a01 += f1; }
        else if (r == 1) { a10 += f0; a11 += f1; }
        else if (r == 2) { a20 += f0; a21 += f1; }
        else             { a30 += f0; a31 += f1; }
    }
    int d0 = deg_key[node * 4 + 0], d1 = deg_key[node * 4 + 1];
    int d2 = deg_key[node * 4 + 2], d3 = deg_key[node * 4 + 3];
    float s0 = 1.0f / (float)(d0 > 1 ? d0 : 1);
    float s1 = 1.0f / (float)(d1 > 1 ? d1 : 1);
    float s2 = 1.0f / (float)(d2 > 1 ? d2 : 1);
    float s3 = 1.0f / (float)(d3 > 1 ? d3 : 1);
    size_t ob = (size_t)row * KT + c;
    *(u32*)(Aout + ob + 0)   = pack2(a00 * s0, a01 * s0);
    *(u32*)(Aout + ob + 128) = pack2(a10 * s1, a11 * s1);
    *(u32*)(Aout + ob + 256) = pack2(a20 * s2, a21 * s2);
    *(u32*)(Aout + ob + 384) = pack2(a30 * s3, a31 * s3);
    *(u32*)(Aout + ob + 512) = *(const u32*)(feat + (size_t)node * FD + c);  // root concat
}

// ---------- GEMM: C[M,128] = act(A[M,640] @ Bt^T + bias) ----------
// Bt is [128][640] (output-col major). 4 waves, 128x128 tile, BK=64.
__global__ __launch_bounds__(256) void gemm640(const u16* __restrict__ A,
                                               const u16* __restrict__ Bt,
                                               const float* __restrict__ bias,
                                               void* __restrict__ Cout,
                                               int M, int relu, int outBf16) {
    __shared__ u16 As[128][72];   // +8 pad: keeps 16B alignment, 2-way-max bank conflict
    int tid = threadIdx.x;
    int wid = tid >> 6, lane = tid & 63;
    int wm = wid >> 1, wn = wid & 1;
    int lr = lane & 15, hi = lane >> 4;
    int row0 = blockIdx.x * 128;

    f32x4 acc[4][4];
#pragma unroll
    for (int i = 0; i < 4; ++i)
#pragma unroll
        for (int j = 0; j < 4; ++j) acc[i][j] = (f32x4){0.f, 0.f, 0.f, 0.f};

    for (int t = 0; t < KT / 64; ++t) {
        // stage A tile: 128 rows x 64 k (bf16)
#pragma unroll
        for (int it = 0; it < 4; ++it) {
            int r = (tid >> 3) + it * 32;
            int seg = tid & 7;
            int grow = row0 + r;
            uint4 v = make_uint4(0, 0, 0, 0);
            if (grow < M)
                v = *reinterpret_cast<const uint4*>(A + (size_t)grow * KT + t * 64 + seg * 8);
            *reinterpret_cast<uint4*>(&As[r][seg * 8]) = v;
        }
        __syncthreads();
#pragma unroll
        for (int kk = 0; kk < 2; ++kk) {
            int k0 = t * 64 + kk * 32 + hi * 8;
            bf16x8 afr[4], bfr[4];
#pragma unroll
            for (int ni = 0; ni < 4; ++ni) {
                int col = wn * 64 + ni * 16 + lr;
                bfr[ni] = *reinterpret_cast<const bf16x8*>(Bt + (size_t)col * KT + k0);
            }
#pragma unroll
            for (int mi = 0; mi < 4; ++mi)
                afr[mi] = *reinterpret_cast<const bf16x8*>(&As[wm * 64 + mi * 16 + lr][kk * 32 + hi * 8]);
#pragma unroll
            for (int mi = 0; mi < 4; ++mi)
#pragma unroll
                for (int ni = 0; ni < 4; ++ni)
                    acc[mi][ni] = __builtin_amdgcn_mfma_f32_16x16x32_bf16(afr[mi], bfr[ni], acc[mi][ni], 0, 0, 0);
        }
        __syncthreads();
    }
    // epilogue: D col = lane&15, row = 4*(lane>>4)+reg
#pragma unroll
    for (int mi = 0; mi < 4; ++mi) {
#pragma unroll
        for (int ni = 0; ni < 4; ++ni) {
            int col = wn * 64 + ni * 16 + lr;
            float bv = bias[col];
#pragma unroll
            for (int rg = 0; rg < 4; ++rg) {
                int row = row0 + wm * 64 + mi * 16 + hi * 4 + rg;
                if (row < M) {
                    float v = acc[mi][ni][rg] + bv;
                    if (relu) v = fmaxf(v, 0.f);
                    if (outBf16) ((u16*)Cout)[(size_t)row * FD + col] = f2b(v);
                    else ((float*)Cout)[(size_t)row * FD + col] = v;
                }
            }
        }
    }
}

// ---------- final FC: out[q, :] = relu([h2[nest_q] | h2[food_q]] @ Wfc + bfc) ----------
__global__ __launch_bounds__(256) void fc_kernel(const float* __restrict__ h2q,
                                                 const float* __restrict__ Wfc,
                                                 const float* __restrict__ bfc,
                                                 float* __restrict__ out) {
    __shared__ float comb[2 * FD];
    int q = blockIdx.x, t = threadIdx.x;
    if (t < FD) comb[t] = h2q[(size_t)q * FD + t];
    else comb[t] = h2q[(size_t)(NQ + q) * FD + (t - FD)];
    __syncthreads();
    float s = bfc[t];
#pragma unroll 4
    for (int k = 0; k < 2 * FD; ++k) s += comb[k] * Wfc[(size_t)k * HIDN + t];
    out[(size_t)q * HIDN + t] = fmaxf(s, 0.f);
}

extern "C" void kernel_launch(void* const* d_in, const int* in_sizes, int n_in,
                              void* d_out, int out_size, void* d_ws, size_t ws_size,
                              hipStream_t stream) {
    const float* x      = (const float*)d_in[0];
    const int*   ei     = (const int*)d_in[1];
    const int*   et     = (const int*)d_in[2];
    const int*   nest   = (const int*)d_in[3];
    const int*   food   = (const int*)d_in[4];
    const float* Wrel1  = (const float*)d_in[5];
    const float* Wroot1 = (const float*)d_in[6];
    const float* b1     = (const float*)d_in[7];
    const float* Wrel2  = (const float*)d_in[8];
    const float* Wroot2 = (const float*)d_in[9];
    const float* b2     = (const float*)d_in[10];
    const float* Wfc    = (const float*)d_in[11];
    const float* bfc    = (const float*)d_in[12];
    float* out = (float*)d_out;

    char* w = (char*)d_ws;
    size_t off = 0;
    auto take = [&](size_t b) {
        char* p = w + off;
        off += b;
        off = (off + 255) & ~(size_t)255;
        return p;
    };
    int* deg_key  = (int*)take((size_t)NN * NR * 4);
    int* offs     = (int*)take(((size_t)NN + 1) * 4);
    int* cursor   = (int*)take((size_t)NN * 4);
    int* chunkTot = (int*)take(1024);
    int* chunkOff = (int*)take(1024);
    int* spack    = (int*)take((size_t)NE * 4);
    u16* xh       = (u16*)take((size_t)NN * FD * 2);
    u16* h1       = (u16*)take((size_t)NN * FD * 2);
    u16* Bt1      = (u16*)take((size_t)FD * KT * 2);
    u16* Bt2      = (u16*)take((size_t)FD * KT * 2);
    u16* A2       = (u16*)take((size_t)2048 * KT * 2);
    float* h2q    = (float*)take((size_t)2048 * FD * 4);
    size_t rem = (ws_size > off) ? (ws_size - off) : 0;
    long chunk_rows = (long)(rem / (KT * 2));
    chunk_rows = (chunk_rows / 128) * 128;
    if (chunk_rows >= NN) chunk_rows = NN;
    if (chunk_rows < 128) chunk_rows = 128;   // best effort
    u16* A1 = (u16*)(w + off);

    hipMemsetAsync(deg_key, 0, (size_t)NN * NR * 4, stream);
    count_kernel<<<(NE + 255) / 256, 256, 0, stream>>>(ei, et, deg_key);
    chunk_sum<<<NCH, 256, 0, stream>>>(deg_key, chunkTot);
    scan_chunks<<<1, 64, 0, stream>>>(chunkTot, chunkOff, offs);
    write_offsets<<<NCH, 256, 0, stream>>>(deg_key, chunkOff, offs, cursor);
    scatter_kernel<<<(NE + 255) / 256, 256, 0, stream>>>(ei, et, cursor, spack);
    cvt_bf16<<<((NN * FD / 4) + 255) / 256, 256, 0, stream>>>(x, xh, NN * FD);
    prep_B<<<(FD * KT + 255) / 256, 256, 0, stream>>>(Wrel1, Wroot1, Bt1);
    prep_B<<<(FD * KT + 255) / 256, 256, 0, stream>>>(Wrel2, Wroot2, Bt2);

    for (long c0 = 0; c0 < NN; c0 += chunk_rows) {
        int rows = (int)((NN - c0 < chunk_rows) ? (NN - c0) : chunk_rows);
        agg_kernel<<<(rows + 3) / 4, 256, 0, stream>>>(offs, deg_key, spack, xh, A1,
                                                       rows, (int)c0, nullptr, nullptr, 0);
        gemm640<<<(rows + 127) / 128, 256, 0, stream>>>(A1, Bt1, b1,
                                                        (void*)(h1 + (size_t)c0 * FD), rows, 1, 1);
    }
    agg_kernel<<<(2048 + 3) / 4, 256, 0, stream>>>(offs, deg_key, spack, h1, A2,
                                                   2048, 0, nest, food, 1);
    gemm640<<<(2048 + 127) / 128, 256, 0, stream>>>(A2, Bt2, b2, (void*)h2q, 2048, 0, 0);
    fc_kernel<<<NQ, 256, 0, stream>>>(h2q, Wfc, bfc, out);
}

// Round 2
// 429.069 us; speedup vs baseline: 1.2771x; 1.2771x over previous
//
#include <hip/hip_runtime.h>
#include <stdint.h>

#define NN 100000
#define NE 1600000
#define NR 4
#define NK (NN * NR)      // 400000 (dst,rel) keys
#define FD 128
#define KT 640            // 512 (rel) + 128 (root)
#define NQ 1024
#define HIDN 256
#define NCH4 ((NK + 1023) / 1024)   // 391 chunks of 1024 keys

using u16 = unsigned short;
using u32 = unsigned int;
typedef __attribute__((ext_vector_type(8))) __bf16 bf16x8;
typedef __attribute__((ext_vector_type(4))) float f32x4;

__device__ __forceinline__ u16 f2b(float f) {
    u32 u = __builtin_bit_cast(u32, f);
    u32 r = u + 0x7FFFu + ((u >> 16) & 1u);   // round-to-nearest-even
    return (u16)(r >> 16);
}
__device__ __forceinline__ float b2f(u16 h) {
    u32 u = ((u32)h) << 16;
    return __builtin_bit_cast(float, u);
}
__device__ __forceinline__ u32 pack2(float a, float b) {
    return (u32)f2b(a) | ((u32)f2b(b) << 16);
}

// ---------- CSR build over (dst,rel) keys ----------
__global__ __launch_bounds__(256) void count_kernel(const int* __restrict__ ei,
                                                    const int* __restrict__ et,
                                                    int* __restrict__ deg) {
    int e = blockIdx.x * 256 + threadIdx.x;
    if (e >= NE) return;
    int dst = ei[NE + e];
    int r = et[e];
    atomicAdd(&deg[dst * NR + r], 1);
}

__global__ __launch_bounds__(256) void chunk_sum(const int* __restrict__ deg,
                                                 int* __restrict__ chunkTot) {
    __shared__ int sm[256];
    int b = blockIdx.x, t = threadIdx.x;
    int base = b * 1024 + t * 4;
    int s = 0;
    for (int j = 0; j < 4; ++j) {
        int k = base + j;
        if (k < NK) s += deg[k];
    }
    sm[t] = s;
    __syncthreads();
    for (int o2 = 128; o2 > 0; o2 >>= 1) {
        if (t < o2) sm[t] += sm[t + o2];
        __syncthreads();
    }
    if (t == 0) chunkTot[b] = sm[0];
}

__global__ __launch_bounds__(512) void scan_chunks(const int* __restrict__ chunkTot,
                                                   int* __restrict__ chunkOff,
                                                   int* __restrict__ offs4) {
    __shared__ int sm[512];
    int t = threadIdx.x;
    int v = (t < NCH4) ? chunkTot[t] : 0;
    sm[t] = v;
    __syncthreads();
    for (int o2 = 1; o2 < 512; o2 <<= 1) {
        int n = (t >= o2) ? sm[t - o2] : 0;
        __syncthreads();
        sm[t] += n;
        __syncthreads();
    }
    if (t < NCH4) chunkOff[t] = sm[t] - v;
    if (t == 0) offs4[NK] = NE;
}

__global__ __launch_bounds__(256) void write_offsets(const int* __restrict__ deg,
                                                     const int* __restrict__ chunkOff,
                                                     int* __restrict__ offs4,
                                                     int* __restrict__ cursor) {
    __shared__ int sm[256];
    int b = blockIdx.x, t = threadIdx.x;
    int base = b * 1024 + t * 4;
    int g[4];
    int s = 0;
    for (int j = 0; j < 4; ++j) {
        int k = base + j;
        g[j] = (k < NK) ? deg[k] : 0;
        s += g[j];
    }
    sm[t] = s;
    __syncthreads();
    for (int o2 = 1; o2 < 256; o2 <<= 1) {
        int v = (t >= o2) ? sm[t - o2] : 0;
        __syncthreads();
        sm[t] += v;
        __syncthreads();
    }
    int excl = sm[t] - s + chunkOff[b];
    for (int j = 0; j < 4; ++j) {
        int k = base + j;
        if (k < NK) {
            offs4[k] = excl;
            cursor[k] = excl;
            excl += g[j];
        }
    }
}

__global__ __launch_bounds__(256) void scatter_kernel(const int* __restrict__ ei,
                                                      const int* __restrict__ et,
                                                      int* __restrict__ cursor,
                                                      int* __restrict__ spack) {
    int e = blockIdx.x * 256 + threadIdx.x;
    if (e >= NE) return;
    int src = ei[e];
    int dst = ei[NE + e];
    int r = et[e];
    int pos = atomicAdd(&cursor[dst * NR + r], 1);
    spack[pos] = src;
}

// ---------- conversions / weight prep ----------
__global__ __launch_bounds__(256) void cvt_bf16(const float* __restrict__ in,
                                                u16* __restrict__ outp, int n) {
    int i = blockIdx.x * 256 + threadIdx.x;
    int idx = i * 4;
    if (idx + 3 >= n) {
        for (int j = idx; j < n; ++j) outp[j] = f2b(in[j]);
        return;
    }
    float4 v = *(const float4*)(in + idx);
    u32 lo = (u32)f2b(v.x) | ((u32)f2b(v.y) << 16);
    u32 hi = (u32)f2b(v.z) | ((u32)f2b(v.w) << 16);
    *(uint2*)(outp + idx) = make_uint2(lo, hi);
}

// Bt[o][k]: k<512 -> W_rel[k*128+o]; k>=512 -> Wroot[(k-512)*128+o]
__global__ __launch_bounds__(256) void prep_B(const float* __restrict__ Wrel,
                                              const float* __restrict__ Wroot,
                                              u16* __restrict__ Bt) {
    int i = blockIdx.x * 256 + threadIdx.x;
    if (i >= FD * KT) return;
    int k = i % KT;
    int o = i / KT;
    float v = (k < 512) ? Wrel[(size_t)k * FD + o] : Wroot[(size_t)(k - 512) * FD + o];
    Bt[i] = f2b(v);
}

// ---------- aggregation: one wave per output row, 8-deep MLP ----------
__global__ __launch_bounds__(256) void agg_kernel(const int* __restrict__ offs4,
                                                  const int* __restrict__ spack,
                                                  const u32* __restrict__ fp,   // feat as u32[node][64]
                                                  u16* __restrict__ Aout,
                                                  int rows, int node_base,
                                                  const int* __restrict__ nest,
                                                  const int* __restrict__ food,
                                                  int qmode) {
    int wid = threadIdx.x >> 6, lane = threadIdx.x & 63;
    int row = blockIdx.x * 4 + wid;
    if (row >= rows) return;
    int node;
    if (qmode) node = (row < NQ) ? nest[row] : food[row - NQ];
    else node = node_base + row;

    int o0 = offs4[node * 4 + 0];
    int o1 = offs4[node * 4 + 1];
    int o2 = offs4[node * 4 + 2];
    int o3 = offs4[node * 4 + 3];
    int o4 = offs4[node * 4 + 4];

    float a00 = 0, a01 = 0, a10 = 0, a11 = 0, a20 = 0, a21 = 0, a30 = 0, a31 = 0;

#define ACCJ(IDX, V)                                             \
    {                                                            \
        float w0 = b2f((u16)((V) & 0xFFFFu));                    \
        float w1 = b2f((u16)((V) >> 16));                        \
        int _ix = (IDX);                                         \
        if (_ix < o1)      { a00 += w0; a01 += w1; }             \
        else if (_ix < o2) { a10 += w0; a11 += w1; }             \
        else if (_ix < o3) { a20 += w0; a21 += w1; }             \
        else               { a30 += w0; a31 += w1; }             \
    }

    int i = o0;
    for (; i + 8 <= o4; i += 8) {
        int p0 = spack[i + 0], p1 = spack[i + 1], p2 = spack[i + 2], p3 = spack[i + 3];
        int p4 = spack[i + 4], p5 = spack[i + 5], p6 = spack[i + 6], p7 = spack[i + 7];
        u32 v0 = fp[(size_t)p0 * 64 + lane];
        u32 v1 = fp[(size_t)p1 * 64 + lane];
        u32 v2 = fp[(size_t)p2 * 64 + lane];
        u32 v3 = fp[(size_t)p3 * 64 + lane];
        u32 v4 = fp[(size_t)p4 * 64 + lane];
        u32 v5 = fp[(size_t)p5 * 64 + lane];
        u32 v6 = fp[(size_t)p6 * 64 + lane];
        u32 v7 = fp[(size_t)p7 * 64 + lane];
        ACCJ(i + 0, v0); ACCJ(i + 1, v1); ACCJ(i + 2, v2); ACCJ(i + 3, v3);
        ACCJ(i + 4, v4); ACCJ(i + 5, v5); ACCJ(i + 6, v6); ACCJ(i + 7, v7);
    }
    for (; i < o4; ++i) {
        int p = spack[i];
        u32 v = fp[(size_t)p * 64 + lane];
        ACCJ(i, v);
    }
#undef ACCJ

    int d0 = o1 - o0, d1 = o2 - o1, d2 = o3 - o2, d3 = o4 - o3;
    float s0 = 1.0f / (float)(d0 > 1 ? d0 : 1);
    float s1 = 1.0f / (float)(d1 > 1 ? d1 : 1);
    float s2 = 1.0f / (float)(d2 > 1 ? d2 : 1);
    float s3 = 1.0f / (float)(d3 > 1 ? d3 : 1);
    size_t ob = (size_t)row * KT + lane * 2;
    u16* Ao = Aout + ob;
    *(u32*)(Ao + 0)   = pack2(a00 * s0, a01 * s0);
    *(u32*)(Ao + 128) = pack2(a10 * s1, a11 * s1);
    *(u32*)(Ao + 256) = pack2(a20 * s2, a21 * s2);
    *(u32*)(Ao + 384) = pack2(a30 * s3, a31 * s3);
    *(u32*)(Ao + 512) = fp[(size_t)node * 64 + lane];   // root concat
}

// ---------- GEMM: C[M,128] = act(A[M,640] @ Bt^T + bias) ----------
__global__ __launch_bounds__(256) void gemm640(const u16* __restrict__ A,
                                               const u16* __restrict__ Bt,
                                               const float* __restrict__ bias,
                                               void* __restrict__ Cout,
                                               int M, int relu, int outBf16) {
    __shared__ u16 As[128][72];   // +8 pad: 16B-aligned, low bank conflict
    int tid = threadIdx.x;
    int wid = tid >> 6, lane = tid & 63;
    int wm = wid >> 1, wn = wid & 1;
    int lr = lane & 15, hi = lane >> 4;
    int row0 = blockIdx.x * 128;

    f32x4 acc[4][4];
#pragma unroll
    for (int i = 0; i < 4; ++i)
#pragma unroll
        for (int j = 0; j < 4; ++j) acc[i][j] = (f32x4){0.f, 0.f, 0.f, 0.f};

    for (int t = 0; t < KT / 64; ++t) {
#pragma unroll
        for (int it = 0; it < 4; ++it) {
            int r = (tid >> 3) + it * 32;
            int seg = tid & 7;
            int grow = row0 + r;
            uint4 v = make_uint4(0, 0, 0, 0);
            if (grow < M)
                v = *reinterpret_cast<const uint4*>(A + (size_t)grow * KT + t * 64 + seg * 8);
            *reinterpret_cast<uint4*>(&As[r][seg * 8]) = v;
        }
        __syncthreads();
#pragma unroll
        for (int kk = 0; kk < 2; ++kk) {
            int k0 = t * 64 + kk * 32 + hi * 8;
            bf16x8 afr[4], bfr[4];
#pragma unroll
            for (int ni = 0; ni < 4; ++ni) {
                int col = wn * 64 + ni * 16 + lr;
                bfr[ni] = *reinterpret_cast<const bf16x8*>(Bt + (size_t)col * KT + k0);
            }
#pragma unroll
            for (int mi = 0; mi < 4; ++mi)
                afr[mi] = *reinterpret_cast<const bf16x8*>(&As[wm * 64 + mi * 16 + lr][kk * 32 + hi * 8]);
#pragma unroll
            for (int mi = 0; mi < 4; ++mi)
#pragma unroll
                for (int ni = 0; ni < 4; ++ni)
                    acc[mi][ni] = __builtin_amdgcn_mfma_f32_16x16x32_bf16(afr[mi], bfr[ni], acc[mi][ni], 0, 0, 0);
        }
        __syncthreads();
    }
#pragma unroll
    for (int mi = 0; mi < 4; ++mi) {
#pragma unroll
        for (int ni = 0; ni < 4; ++ni) {
            int col = wn * 64 + ni * 16 + lr;
            float bv = bias[col];
#pragma unroll
            for (int rg = 0; rg < 4; ++rg) {
                int row = row0 + wm * 64 + mi * 16 + hi * 4 + rg;
                if (row < M) {
                    float v = acc[mi][ni][rg] + bv;
                    if (relu) v = fmaxf(v, 0.f);
                    if (outBf16) ((u16*)Cout)[(size_t)row * FD + col] = f2b(v);
                    else ((float*)Cout)[(size_t)row * FD + col] = v;
                }
            }
        }
    }
}

// ---------- final FC ----------
__global__ __launch_bounds__(256) void fc_kernel(const float* __restrict__ h2q,
                                                 const float* __restrict__ Wfc,
                                                 const float* __restrict__ bfc,
                                                 float* __restrict__ out) {
    __shared__ float comb[2 * FD];
    int q = blockIdx.x, t = threadIdx.x;
    if (t < FD) comb[t] = h2q[(size_t)q * FD + t];
    else comb[t] = h2q[(size_t)(NQ + q) * FD + (t - FD)];
    __syncthreads();
    float s = bfc[t];
#pragma unroll 4
    for (int k = 0; k < 2 * FD; ++k) s += comb[k] * Wfc[(size_t)k * HIDN + t];
    out[(size_t)q * HIDN + t] = fmaxf(s, 0.f);
}

extern "C" void kernel_launch(void* const* d_in, const int* in_sizes, int n_in,
                              void* d_out, int out_size, void* d_ws, size_t ws_size,
                              hipStream_t stream) {
    const float* x      = (const float*)d_in[0];
    const int*   ei     = (const int*)d_in[1];
    const int*   et     = (const int*)d_in[2];
    const int*   nest   = (const int*)d_in[3];
    const int*   food   = (const int*)d_in[4];
    const float* Wrel1  = (const float*)d_in[5];
    const float* Wroot1 = (const float*)d_in[6];
    const float* b1     = (const float*)d_in[7];
    const float* Wrel2  = (const float*)d_in[8];
    const float* Wroot2 = (const float*)d_in[9];
    const float* b2     = (const float*)d_in[10];
    const float* Wfc    = (const float*)d_in[11];
    const float* bfc    = (const float*)d_in[12];
    float* out = (float*)d_out;

    char* w = (char*)d_ws;
    size_t off = 0;
    auto take = [&](size_t b) {
        char* p = w + off;
        off += b;
        off = (off + 255) & ~(size_t)255;
        return p;
    };
    int* deg      = (int*)take((size_t)NK * 4);
    int* offs4    = (int*)take(((size_t)NK + 1) * 4);
    int* cursor   = (int*)take((size_t)NK * 4);
    int* chunkTot = (int*)take((size_t)NCH4 * 4);
    int* chunkOff = (int*)take((size_t)NCH4 * 4);
    int* spack    = (int*)take((size_t)NE * 4);
    u16* xh       = (u16*)take((size_t)NN * FD * 2);
    u16* h1       = (u16*)take((size_t)NN * FD * 2);
    u16* Bt1      = (u16*)take((size_t)FD * KT * 2);
    u16* Bt2      = (u16*)take((size_t)FD * KT * 2);
    u16* A2       = (u16*)take((size_t)2048 * KT * 2);
    float* h2q    = (float*)take((size_t)2048 * FD * 4);
    size_t rem = (ws_size > off) ? (ws_size - off) : 0;
    long chunk_rows = (long)(rem / (KT * 2));
    chunk_rows = (chunk_rows / 128) * 128;
    if (chunk_rows >= NN) chunk_rows = NN;
    if (chunk_rows < 128) chunk_rows = 128;   // best effort
    u16* A1 = (u16*)(w + off);

    hipMemsetAsync(deg, 0, (size_t)NK * 4, stream);
    count_kernel<<<(NE + 255) / 256, 256, 0, stream>>>(ei, et, deg);
    chunk_sum<<<NCH4, 256, 0, stream>>>(deg, chunkTot);
    scan_chunks<<<1, 512, 0, stream>>>(chunkTot, chunkOff, offs4);
    write_offsets<<<NCH4, 256, 0, stream>>>(deg, chunkOff, offs4, cursor);
    scatter_kernel<<<(NE + 255) / 256, 256, 0, stream>>>(ei, et, cursor, spack);
    cvt_bf16<<<((NN * FD / 4) + 255) / 256, 256, 0, stream>>>(x, xh, NN * FD);
    prep_B<<<(FD * KT + 255) / 256, 256, 0, stream>>>(Wrel1, Wroot1, Bt1);
    prep_B<<<(FD * KT + 255) / 256, 256, 0, stream>>>(Wrel2, Wroot2, Bt2);

    for (long c0 = 0; c0 < NN; c0 += chunk_rows) {
        int rows = (int)((NN - c0 < chunk_rows) ? (NN - c0) : chunk_rows);
        agg_kernel<<<(rows + 3) / 4, 256, 0, stream>>>(offs4, spack, (const u32*)xh, A1,
                                                       rows, (int)c0, nullptr, nullptr, 0);
        gemm640<<<(rows + 127) / 128, 256, 0, stream>>>(A1, Bt1, b1,
                                                        (void*)(h1 + (size_t)c0 * FD), rows, 1, 1);
    }
    agg_kernel<<<(2048 + 3) / 4, 256, 0, stream>>>(offs4, spack, (const u32*)h1, A2,
                                                   2048, 0, nest, food, 1);
    gemm640<<<(2048 + 127) / 128, 256, 0, stream>>>(A2, Bt2, b2, (void*)h2q, 2048, 0, 0);
    fc_kernel<<<NQ, 256, 0, stream>>>(h2q, Wfc, bfc, out);
}

// Round 3
// 372.838 us; speedup vs baseline: 1.4697x; 1.1508x over previous
//
#include <hip/hip_runtime.h>
#include <stdint.h>

#define NN 100000
#define NE 1600000
#define NR 4
#define NK (NN * NR)      // 400000 (dst,rel) keys
#define FD 128
#define KT 640            // 512 (rel) + 128 (root)
#define NQ 1024
#define HIDN 256
#define NCH4 ((NK + 1023) / 1024)   // 391 chunks of 1024 keys

#define NB 391            // dst buckets of 256 nodes (100000 >> 8 -> 0..390)
#define BSH 8
#define EPB 2048          // edges per bucket_scatter block
#define NBLK1 ((NE + EPB - 1) / EPB)   // 782

using u16 = unsigned short;
using u32 = unsigned int;
typedef __attribute__((ext_vector_type(8))) __bf16 bf16x8;
typedef __attribute__((ext_vector_type(4))) float f32x4;

__device__ __forceinline__ u16 f2b(float f) {
    u32 u = __builtin_bit_cast(u32, f);
    u32 r = u + 0x7FFFu + ((u >> 16) & 1u);   // round-to-nearest-even
    return (u16)(r >> 16);
}
__device__ __forceinline__ float b2f(u16 h) {
    u32 u = ((u32)h) << 16;
    return __builtin_bit_cast(float, u);
}
__device__ __forceinline__ u32 pack2(float a, float b) {
    return (u32)f2b(a) | ((u32)f2b(b) << 16);
}

// ---------- CSR build over (dst,rel) keys ----------
__global__ __launch_bounds__(256) void count_kernel(const int* __restrict__ ei,
                                                    const int* __restrict__ et,
                                                    int* __restrict__ deg) {
    int e = blockIdx.x * 256 + threadIdx.x;
    if (e >= NE) return;
    int dst = __builtin_nontemporal_load(ei + NE + e);
    int r = __builtin_nontemporal_load(et + e);
    atomicAdd(&deg[dst * NR + r], 1);
}

__global__ __launch_bounds__(256) void chunk_sum(const int* __restrict__ deg,
                                                 int* __restrict__ chunkTot) {
    __shared__ int sm[256];
    int b = blockIdx.x, t = threadIdx.x;
    int base = b * 1024 + t * 4;
    int s = 0;
    for (int j = 0; j < 4; ++j) {
        int k = base + j;
        if (k < NK) s += deg[k];
    }
    sm[t] = s;
    __syncthreads();
    for (int o2 = 128; o2 > 0; o2 >>= 1) {
        if (t < o2) sm[t] += sm[t + o2];
        __syncthreads();
    }
    if (t == 0) chunkTot[b] = sm[0];
}

__global__ __launch_bounds__(512) void scan_chunks(const int* __restrict__ chunkTot,
                                                   int* __restrict__ chunkOff,
                                                   int* __restrict__ offs4) {
    __shared__ int sm[512];
    int t = threadIdx.x;
    int v = (t < NCH4) ? chunkTot[t] : 0;
    sm[t] = v;
    __syncthreads();
    for (int o2 = 1; o2 < 512; o2 <<= 1) {
        int n = (t >= o2) ? sm[t - o2] : 0;
        __syncthreads();
        sm[t] += n;
        __syncthreads();
    }
    if (t < NCH4) chunkOff[t] = sm[t] - v;
    if (t == 0) offs4[NK] = NE;
}

__global__ __launch_bounds__(256) void write_offsets(const int* __restrict__ deg,
                                                     const int* __restrict__ chunkOff,
                                                     int* __restrict__ offs4) {
    __shared__ int sm[256];
    int b = blockIdx.x, t = threadIdx.x;
    int base = b * 1024 + t * 4;
    int g[4];
    int s = 0;
    for (int j = 0; j < 4; ++j) {
        int k = base + j;
        g[j] = (k < NK) ? deg[k] : 0;
        s += g[j];
    }
    sm[t] = s;
    __syncthreads();
    for (int o2 = 1; o2 < 256; o2 <<= 1) {
        int v = (t >= o2) ? sm[t - o2] : 0;
        __syncthreads();
        sm[t] += v;
        __syncthreads();
    }
    int excl = sm[t] - s + chunkOff[b];
    for (int j = 0; j < 4; ++j) {
        int k = base + j;
        if (k < NK) {
            offs4[k] = excl;
            excl += g[j];
        }
    }
}

__global__ __launch_bounds__(512) void init_bcur(const int* __restrict__ offs4,
                                                 int* __restrict__ bcur) {
    int b = blockIdx.x * 512 + threadIdx.x;
    if (b < NB) bcur[b] = offs4[b << 10];
}

// ---------- phase 1: bucket scatter (contiguous per-block runs per bucket) ----------
__global__ __launch_bounds__(256) void bucket_scatter(const int* __restrict__ ei,
                                                      const int* __restrict__ et,
                                                      int* __restrict__ bcur,
                                                      u32* __restrict__ bpack) {
    __shared__ int hist[NB];
    __shared__ int base[NB];
    int t = threadIdx.x;
    for (int i = t; i < NB; i += 256) hist[i] = 0;
    __syncthreads();
    int e0 = blockIdx.x * EPB;
    int rank[8];
    u32 pk[8];
    int bk[8];
#pragma unroll
    for (int j = 0; j < 8; ++j) {
        int e = e0 + j * 256 + t;
        bk[j] = -1;
        if (e < NE) {
            int src = __builtin_nontemporal_load(ei + e);
            int dst = __builtin_nontemporal_load(ei + NE + e);
            int r   = __builtin_nontemporal_load(et + e);
            bk[j] = dst >> BSH;
            pk[j] = (u32)src | ((u32)r << 17) | ((u32)(dst & 255) << 19);
            rank[j] = atomicAdd(&hist[bk[j]], 1);
        }
    }
    __syncthreads();
    for (int i = t; i < NB; i += 256) {
        int h = hist[i];
        base[i] = h ? atomicAdd(&bcur[i], h) : 0;
    }
    __syncthreads();
#pragma unroll
    for (int j = 0; j < 8; ++j)
        if (bk[j] >= 0) bpack[base[bk[j]] + rank[j]] = pk[j];
}

// ---------- phase 2: key scatter, one block owns one bucket, cursors in LDS ----------
__global__ __launch_bounds__(256) void key_scatter(const int* __restrict__ offs4,
                                                   const u32* __restrict__ bpack,
                                                   int* __restrict__ spack) {
    __shared__ int lcur[1024];
    int b = blockIdx.x, t = threadIdx.x;
    int k0 = b << 10;
#pragma unroll
    for (int j = 0; j < 4; ++j) {
        int k = k0 + t + j * 256;
        lcur[t + j * 256] = offs4[k > NK ? NK : k];
    }
    __syncthreads();
    int kend = k0 + 1024;
    if (kend > NK) kend = NK;
    int e0 = offs4[k0];
    int e1 = offs4[kend];
    for (int i = e0 + t; i < e1; i += 256) {
        u32 pk = __builtin_nontemporal_load(bpack + i);
        int src = pk & 0x1FFFF;
        int idx = pk >> 17;                 // (dstlow<<2) | r
        int pos = atomicAdd(&lcur[idx], 1);
        spack[pos] = src;
    }
}

// ---------- conversions / weight prep ----------
__global__ __launch_bounds__(256) void cvt_bf16(const float* __restrict__ in,
                                                u16* __restrict__ outp, int n) {
    int i = blockIdx.x * 256 + threadIdx.x;
    int idx = i * 4;
    if (idx + 3 >= n) {
        for (int j = idx; j < n; ++j) outp[j] = f2b(in[j]);
        return;
    }
    float4 v = *(const float4*)(in + idx);
    u32 lo = (u32)f2b(v.x) | ((u32)f2b(v.y) << 16);
    u32 hi = (u32)f2b(v.z) | ((u32)f2b(v.w) << 16);
    *(uint2*)(outp + idx) = make_uint2(lo, hi);
}

// Bt[o][k]: k<512 -> W_rel[k*128+o]; k>=512 -> Wroot[(k-512)*128+o]
__global__ __launch_bounds__(256) void prep_B(const float* __restrict__ Wrel,
                                              const float* __restrict__ Wroot,
                                              u16* __restrict__ Bt) {
    int i = blockIdx.x * 256 + threadIdx.x;
    if (i >= FD * KT) return;
    int k = i % KT;
    int o = i / KT;
    float v = (k < 512) ? Wrel[(size_t)k * FD + o] : Wroot[(size_t)(k - 512) * FD + o];
    Bt[i] = f2b(v);
}

// ---------- aggregation: one wave per output row, 8-deep MLP ----------
__global__ __launch_bounds__(256) void agg_kernel(const int* __restrict__ offs4,
                                                  const int* __restrict__ spack,
                                                  const u32* __restrict__ fp,   // feat as u32[node][64]
                                                  u16* __restrict__ Aout,
                                                  int rows, int node_base,
                                                  const int* __restrict__ nest,
                                                  const int* __restrict__ food,
                                                  int qmode) {
    int wid = threadIdx.x >> 6, lane = threadIdx.x & 63;
    int row = blockIdx.x * 4 + wid;
    if (row >= rows) return;
    int node;
    if (qmode) node = (row < NQ) ? nest[row] : food[row - NQ];
    else node = node_base + row;

    int o0 = offs4[node * 4 + 0];
    int o1 = offs4[node * 4 + 1];
    int o2 = offs4[node * 4 + 2];
    int o3 = offs4[node * 4 + 3];
    int o4 = offs4[node * 4 + 4];

    float a00 = 0, a01 = 0, a10 = 0, a11 = 0, a20 = 0, a21 = 0, a30 = 0, a31 = 0;

#define ACCJ(IDX, V)                                             \
    {                                                            \
        float w0 = b2f((u16)((V) & 0xFFFFu));                    \
        float w1 = b2f((u16)((V) >> 16));                        \
        int _ix = (IDX);                                         \
        if (_ix < o1)      { a00 += w0; a01 += w1; }             \
        else if (_ix < o2) { a10 += w0; a11 += w1; }             \
        else if (_ix < o3) { a20 += w0; a21 += w1; }             \
        else               { a30 += w0; a31 += w1; }             \
    }

    int i = o0;
    for (; i + 8 <= o4; i += 8) {
        int p0 = spack[i + 0], p1 = spack[i + 1], p2 = spack[i + 2], p3 = spack[i + 3];
        int p4 = spack[i + 4], p5 = spack[i + 5], p6 = spack[i + 6], p7 = spack[i + 7];
        u32 v0 = fp[(size_t)p0 * 64 + lane];
        u32 v1 = fp[(size_t)p1 * 64 + lane];
        u32 v2 = fp[(size_t)p2 * 64 + lane];
        u32 v3 = fp[(size_t)p3 * 64 + lane];
        u32 v4 = fp[(size_t)p4 * 64 + lane];
        u32 v5 = fp[(size_t)p5 * 64 + lane];
        u32 v6 = fp[(size_t)p6 * 64 + lane];
        u32 v7 = fp[(size_t)p7 * 64 + lane];
        ACCJ(i + 0, v0); ACCJ(i + 1, v1); ACCJ(i + 2, v2); ACCJ(i + 3, v3);
        ACCJ(i + 4, v4); ACCJ(i + 5, v5); ACCJ(i + 6, v6); ACCJ(i + 7, v7);
    }
    for (; i < o4; ++i) {
        int p = spack[i];
        u32 v = fp[(size_t)p * 64 + lane];
        ACCJ(i, v);
    }
#undef ACCJ

    int d0 = o1 - o0, d1 = o2 - o1, d2 = o3 - o2, d3 = o4 - o3;
    float s0 = 1.0f / (float)(d0 > 1 ? d0 : 1);
    float s1 = 1.0f / (float)(d1 > 1 ? d1 : 1);
    float s2 = 1.0f / (float)(d2 > 1 ? d2 : 1);
    float s3 = 1.0f / (float)(d3 > 1 ? d3 : 1);
    size_t ob = (size_t)row * KT + lane * 2;
    u16* Ao = Aout + ob;
    *(u32*)(Ao + 0)   = pack2(a00 * s0, a01 * s0);
    *(u32*)(Ao + 128) = pack2(a10 * s1, a11 * s1);
    *(u32*)(Ao + 256) = pack2(a20 * s2, a21 * s2);
    *(u32*)(Ao + 384) = pack2(a30 * s3, a31 * s3);
    *(u32*)(Ao + 512) = fp[(size_t)node * 64 + lane];   // root concat
}

// ---------- GEMM: C[M,128] = act(A[M,640] @ Bt^T + bias) ----------
__global__ __launch_bounds__(256) void gemm640(const u16* __restrict__ A,
                                               const u16* __restrict__ Bt,
                                               const float* __restrict__ bias,
                                               void* __restrict__ Cout,
                                               int M, int relu, int outBf16) {
    __shared__ u16 As[128][72];   // +8 pad: 16B-aligned, low bank conflict
    int tid = threadIdx.x;
    int wid = tid >> 6, lane = tid & 63;
    int wm = wid >> 1, wn = wid & 1;
    int lr = lane & 15, hi = lane >> 4;
    int row0 = blockIdx.x * 128;

    f32x4 acc[4][4];
#pragma unroll
    for (int i = 0; i < 4; ++i)
#pragma unroll
        for (int j = 0; j < 4; ++j) acc[i][j] = (f32x4){0.f, 0.f, 0.f, 0.f};

    for (int t = 0; t < KT / 64; ++t) {
#pragma unroll
        for (int it = 0; it < 4; ++it) {
            int r = (tid >> 3) + it * 32;
            int seg = tid & 7;
            int grow = row0 + r;
            uint4 v = make_uint4(0, 0, 0, 0);
            if (grow < M)
                v = *reinterpret_cast<const uint4*>(A + (size_t)grow * KT + t * 64 + seg * 8);
            *reinterpret_cast<uint4*>(&As[r][seg * 8]) = v;
        }
        __syncthreads();
#pragma unroll
        for (int kk = 0; kk < 2; ++kk) {
            int k0 = t * 64 + kk * 32 + hi * 8;
            bf16x8 afr[4], bfr[4];
#pragma unroll
            for (int ni = 0; ni < 4; ++ni) {
                int col = wn * 64 + ni * 16 + lr;
                bfr[ni] = *reinterpret_cast<const bf16x8*>(Bt + (size_t)col * KT + k0);
            }
#pragma unroll
            for (int mi = 0; mi < 4; ++mi)
                afr[mi] = *reinterpret_cast<const bf16x8*>(&As[wm * 64 + mi * 16 + lr][kk * 32 + hi * 8]);
#pragma unroll
            for (int mi = 0; mi < 4; ++mi)
#pragma unroll
                for (int ni = 0; ni < 4; ++ni)
                    acc[mi][ni] = __builtin_amdgcn_mfma_f32_16x16x32_bf16(afr[mi], bfr[ni], acc[mi][ni], 0, 0, 0);
        }
        __syncthreads();
    }
#pragma unroll
    for (int mi = 0; mi < 4; ++mi) {
#pragma unroll
        for (int ni = 0; ni < 4; ++ni) {
            int col = wn * 64 + ni * 16 + lr;
            float bv = bias[col];
#pragma unroll
            for (int rg = 0; rg < 4; ++rg) {
                int row = row0 + wm * 64 + mi * 16 + hi * 4 + rg;
                if (row < M) {
                    float v = acc[mi][ni][rg] + bv;
                    if (relu) v = fmaxf(v, 0.f);
                    if (outBf16) ((u16*)Cout)[(size_t)row * FD + col] = f2b(v);
                    else ((float*)Cout)[(size_t)row * FD + col] = v;
                }
            }
        }
    }
}

// ---------- final FC ----------
__global__ __launch_bounds__(256) void fc_kernel(const float* __restrict__ h2q,
                                                 const float* __restrict__ Wfc,
                                                 const float* __restrict__ bfc,
                                                 float* __restrict__ out) {
    __shared__ float comb[2 * FD];
    int q = blockIdx.x, t = threadIdx.x;
    if (t < FD) comb[t] = h2q[(size_t)q * FD + t];
    else comb[t] = h2q[(size_t)(NQ + q) * FD + (t - FD)];
    __syncthreads();
    float s = bfc[t];
#pragma unroll 4
    for (int k = 0; k < 2 * FD; ++k) s += comb[k] * Wfc[(size_t)k * HIDN + t];
    out[(size_t)q * HIDN + t] = fmaxf(s, 0.f);
}

extern "C" void kernel_launch(void* const* d_in, const int* in_sizes, int n_in,
                              void* d_out, int out_size, void* d_ws, size_t ws_size,
                              hipStream_t stream) {
    const float* x      = (const float*)d_in[0];
    const int*   ei     = (const int*)d_in[1];
    const int*   et     = (const int*)d_in[2];
    const int*   nest   = (const int*)d_in[3];
    const int*   food   = (const int*)d_in[4];
    const float* Wrel1  = (const float*)d_in[5];
    const float* Wroot1 = (const float*)d_in[6];
    const float* b1     = (const float*)d_in[7];
    const float* Wrel2  = (const float*)d_in[8];
    const float* Wroot2 = (const float*)d_in[9];
    const float* b2     = (const float*)d_in[10];
    const float* Wfc    = (const float*)d_in[11];
    const float* bfc    = (const float*)d_in[12];
    float* out = (float*)d_out;

    char* w = (char*)d_ws;
    size_t off = 0;
    auto take = [&](size_t b) {
        char* p = w + off;
        off += b;
        off = (off + 255) & ~(size_t)255;
        return p;
    };
    int* deg      = (int*)take((size_t)NK * 4);
    int* offs4    = (int*)take(((size_t)NK + 1) * 4);
    int* chunkTot = (int*)take((size_t)NCH4 * 4);
    int* chunkOff = (int*)take((size_t)NCH4 * 4);
    int* bcur     = (int*)take((size_t)NB * 4);
    u32* bpack    = (u32*)take((size_t)NE * 4);
    int* spack    = (int*)take((size_t)NE * 4);
    u16* xh       = (u16*)take((size_t)NN * FD * 2);
    u16* h1       = (u16*)take((size_t)NN * FD * 2);
    u16* Bt1      = (u16*)take((size_t)FD * KT * 2);
    u16* Bt2      = (u16*)take((size_t)FD * KT * 2);
    u16* A2       = (u16*)take((size_t)2048 * KT * 2);
    float* h2q    = (float*)take((size_t)2048 * FD * 4);
    size_t rem = (ws_size > off) ? (ws_size - off) : 0;
    long chunk_rows = (long)(rem / (KT * 2));
    chunk_rows = (chunk_rows / 128) * 128;
    if (chunk_rows >= NN) chunk_rows = NN;
    if (chunk_rows < 128) chunk_rows = 128;   // best effort
    u16* A1 = (u16*)(w + off);

    hipMemsetAsync(deg, 0, (size_t)NK * 4, stream);
    count_kernel<<<(NE + 255) / 256, 256, 0, stream>>>(ei, et, deg);
    chunk_sum<<<NCH4, 256, 0, stream>>>(deg, chunkTot);
    scan_chunks<<<1, 512, 0, stream>>>(chunkTot, chunkOff, offs4);
    write_offsets<<<NCH4, 256, 0, stream>>>(deg, chunkOff, offs4);
    init_bcur<<<1, 512, 0, stream>>>(offs4, bcur);
    bucket_scatter<<<NBLK1, 256, 0, stream>>>(ei, et, bcur, bpack);
    key_scatter<<<NB, 256, 0, stream>>>(offs4, bpack, spack);
    cvt_bf16<<<((NN * FD / 4) + 255) / 256, 256, 0, stream>>>(x, xh, NN * FD);
    prep_B<<<(FD * KT + 255) / 256, 256, 0, stream>>>(Wrel1, Wroot1, Bt1);
    prep_B<<<(FD * KT + 255) / 256, 256, 0, stream>>>(Wrel2, Wroot2, Bt2);

    for (long c0 = 0; c0 < NN; c0 += chunk_rows) {
        int rows = (int)((NN - c0 < chunk_rows) ? (NN - c0) : chunk_rows);
        agg_kernel<<<(rows + 3) / 4, 256, 0, stream>>>(offs4, spack, (const u32*)xh, A1,
                                                       rows, (int)c0, nullptr, nullptr, 0);
        gemm640<<<(rows + 127) / 128, 256, 0, stream>>>(A1, Bt1, b1,
                                                        (void*)(h1 + (size_t)c0 * FD), rows, 1, 1);
    }
    agg_kernel<<<(2048 + 3) / 4, 256, 0, stream>>>(offs4, spack, (const u32*)h1, A2,
                                                   2048, 0, nest, food, 1);
    gemm640<<<(2048 + 127) / 128, 256, 0, stream>>>(A2, Bt2, b2, (void*)h2q, 2048, 0, 0);
    fc_kernel<<<NQ, 256, 0, stream>>>(h2q, Wfc, bfc, out);
}